// Round 1
// baseline (76.330 us; speedup 1.0000x reference)
//
#include <hip/hip_runtime.h>

#define T_SEQ 4096
#define NBATCH 2
#define DM 1024
#define DI 32
#define NH 4
#define NCOLS 164      // 128 q + 32 k + 4 w
#define NCOLS_PAD 176  // 11 tiles of 16

typedef __attribute__((ext_vector_type(8))) short bf16x8;
typedef __attribute__((ext_vector_type(4))) float f32x4;

__device__ __forceinline__ unsigned short f2bf(float f) {
    unsigned int u = __builtin_bit_cast(unsigned int, f);
    u += 0x7FFFu + ((u >> 16) & 1u);   // RNE; inputs have no NaN
    return (unsigned short)(u >> 16);
}

// ---------------- prep: W^T -> bf16 [176][1024], bias[176] ----------------
__global__ __launch_bounds__(256) void prep_kernel(
    const float* __restrict__ Wq, const float* __restrict__ bq,
    const float* __restrict__ Wk, const float* __restrict__ bk,
    const float* __restrict__ Ww, const float* __restrict__ bw,
    unsigned short* __restrict__ WT, float* __restrict__ bias) {
    int c = blockIdx.x;                    // 0..175
    const float* src = nullptr; int stride = 0; float bv = 0.f;
    if (c < 128)      { src = Wq + c;       stride = NH * DI; bv = bq[c]; }
    else if (c < 160) { src = Wk + (c-128); stride = DI;      bv = bk[c-128]; }
    else if (c < 164) { src = Ww + (c-160); stride = NH;      bv = bw[c-160]; }
    for (int k = threadIdx.x; k < DM; k += blockDim.x) {
        float v = src ? src[(size_t)k * stride] : 0.f;
        WT[(size_t)c * DM + k] = f2bf(v);
    }
    if (threadIdx.x == 0) bias[c] = bv;
}

// ---------------- projection: [8192 x 176] = x[8192 x 1024] * W ----------------
// one wave = one 16-row tile, owns 6 (or 5) col-tiles of 16; K loop 1024/32
__global__ __launch_bounds__(256) void proj_kernel(
    const float* __restrict__ x, const unsigned short* __restrict__ WT,
    const float* __restrict__ bias,
    unsigned short* __restrict__ qws, unsigned short* __restrict__ kws,
    float* __restrict__ wws) {
    int wave = threadIdx.x >> 6;
    int lane = threadIdx.x & 63;
    int gw = blockIdx.x * 4 + wave;        // 0..1023
    int rowTile = gw >> 1;                 // 0..511
    int half = gw & 1;
    int ct0 = half ? 6 : 0;
    int nct = half ? 5 : 6;
    int lr = lane & 15, kg = lane >> 4;
    int r0 = rowTile * 16;

    // A-fragment source row (row index r = b*T + t; x is [T][B][D])
    int rowA = r0 + lr;
    int tA = rowA & (T_SEQ - 1), bA = rowA >> 12;
    const float* xrow = x + ((size_t)tA * NBATCH + bA) * DM;

    f32x4 acc[6] = {};
    for (int k0 = 0; k0 < DM; k0 += 32) {
        const float* xp = xrow + k0 + kg * 8;
        f32x4 a0 = *(const f32x4*)xp;
        f32x4 a1 = *(const f32x4*)(xp + 4);
        bf16x8 af;
        af[0] = (short)f2bf(a0[0]); af[1] = (short)f2bf(a0[1]);
        af[2] = (short)f2bf(a0[2]); af[3] = (short)f2bf(a0[3]);
        af[4] = (short)f2bf(a1[0]); af[5] = (short)f2bf(a1[1]);
        af[6] = (short)f2bf(a1[2]); af[7] = (short)f2bf(a1[3]);
        #pragma unroll
        for (int i = 0; i < 6; ++i) {
            if (i < nct) {   // wave-uniform
                int c = (ct0 + i) * 16 + lr;
                bf16x8 bfg = *(const bf16x8*)(WT + (size_t)c * DM + k0 + kg * 8);
                acc[i] = __builtin_amdgcn_mfma_f32_16x16x32_bf16(af, bfg, acc[i], 0, 0, 0);
            }
        }
    }
    // epilogue: D col = lane&15, row = (lane>>4)*4 + reg
    #pragma unroll
    for (int i = 0; i < 6; ++i) {
        if (i < nct) {
            int cout = (ct0 + i) * 16 + lr;
            float bv = bias[cout];
            #pragma unroll
            for (int r = 0; r < 4; ++r) {
                int rr = r0 + kg * 4 + r;
                int tt = rr & (T_SEQ - 1), bb = rr >> 12;
                float v = acc[i][r] + bv;
                size_t rowoff = (size_t)bb * T_SEQ + tt;
                if (cout < 128)       qws[rowoff * 128 + cout] = f2bf(v);
                else if (cout < 160)  kws[rowoff * 32 + (cout - 128)] = f2bf(v);
                else if (cout < 164)  wws[rowoff * 4 + (cout - 160)] = v;
            }
        }
    }
}

// ---------------- main: out[b][t][s] = sum_h relu(q_h . k) * w_h ----------------
// one wave = (b, 16-row t-tile, 256-col s-strip); 16 s-tiles per wave
__global__ __launch_bounds__(256) void indexer_kernel(
    const unsigned short* __restrict__ qws, const unsigned short* __restrict__ kws,
    const float* __restrict__ wws, float* __restrict__ out) {
    int wave = threadIdx.x >> 6;
    int lane = threadIdx.x & 63;
    int gw = blockIdx.x * 4 + wave;        // 0..8191
    int strip = gw & 15;
    int t16 = (gw >> 4) & 255;
    int b = gw >> 12;
    int t0 = t16 * 16;
    int lr = lane & 15, kg = lane >> 4;

    // A fragments: 4 heads of q for this t-tile (row = lane%16, k = kg*8..+8)
    const unsigned short* qrow = qws + ((size_t)b * T_SEQ + t0 + lr) * 128;
    bf16x8 qf[4];
    #pragma unroll
    for (int h = 0; h < 4; ++h)
        qf[h] = *(const bf16x8*)(qrow + h * 32 + kg * 8);

    // head weights for this lane's 4 output rows (row = kg*4 + reg)
    f32x4 w4[4];
    #pragma unroll
    for (int r = 0; r < 4; ++r)
        w4[r] = *(const f32x4*)(wws + ((size_t)b * T_SEQ + t0 + kg * 4 + r) * 4);

    float* outb = out + (size_t)b * T_SEQ * T_SEQ;
    const unsigned short* kbase = kws + (size_t)b * T_SEQ * 32;
    int sbase = strip * 256;

    for (int st = 0; st < 16; ++st) {
        int s0 = sbase + st * 16;
        bf16x8 kf = *(const bf16x8*)(kbase + (size_t)(s0 + lr) * 32 + kg * 8);
        f32x4 z = {0.f, 0.f, 0.f, 0.f};
        f32x4 a0 = __builtin_amdgcn_mfma_f32_16x16x32_bf16(qf[0], kf, z, 0, 0, 0);
        f32x4 a1 = __builtin_amdgcn_mfma_f32_16x16x32_bf16(qf[1], kf, z, 0, 0, 0);
        f32x4 a2 = __builtin_amdgcn_mfma_f32_16x16x32_bf16(qf[2], kf, z, 0, 0, 0);
        f32x4 a3 = __builtin_amdgcn_mfma_f32_16x16x32_bf16(qf[3], kf, z, 0, 0, 0);
        #pragma unroll
        for (int r = 0; r < 4; ++r) {
            float v = fmaxf(a0[r], 0.f) * w4[r][0] + fmaxf(a1[r], 0.f) * w4[r][1]
                    + fmaxf(a2[r], 0.f) * w4[r][2] + fmaxf(a3[r], 0.f) * w4[r][3];
            outb[(size_t)(t0 + kg * 4 + r) * T_SEQ + (s0 + lr)] = v;
        }
    }
}

extern "C" void kernel_launch(void* const* d_in, const int* in_sizes, int n_in,
                              void* d_out, int out_size, void* d_ws, size_t ws_size,
                              hipStream_t stream) {
    const float* x  = (const float*)d_in[0];
    const float* Wq = (const float*)d_in[1];
    const float* bq = (const float*)d_in[2];
    const float* Wk = (const float*)d_in[3];
    const float* bk = (const float*)d_in[4];
    const float* Ww = (const float*)d_in[5];
    const float* bw = (const float*)d_in[6];
    float* out = (float*)d_out;

    char* ws = (char*)d_ws;
    unsigned short* WT  = (unsigned short*)(ws);            // 176*1024*2 = 360448 B
    float* bias         = (float*)(ws + 360448);            // 704 B
    unsigned short* qws = (unsigned short*)(ws + 524288);   // 2*4096*128*2 = 2 MB
    unsigned short* kws = (unsigned short*)(ws + 2621440);  // 2*4096*32*2 = 512 KB
    float* wws          = (float*)(ws + 3145728);           // 2*4096*4*4 = 128 KB

    prep_kernel<<<dim3(NCOLS_PAD), dim3(256), 0, stream>>>(Wq, bq, Wk, bk, Ww, bw, WT, bias);
    proj_kernel<<<dim3(256), dim3(256), 0, stream>>>(x, WT, bias, qws, kws, wws);
    indexer_kernel<<<dim3(2048), dim3(256), 0, stream>>>(qws, kws, wws, out);
}